// Round 8
// baseline (269.424 us; speedup 1.0000x reference)
//
#include <hip/hip_runtime.h>
#include <hip/hip_bf16.h>

#define B_SZ  4096
#define IN_F  512
#define OUT_F 512
#define NC    64
#define PAIRS 32768               // OUT_F * NC
#define TOT   (IN_F * PAIRS)      // 16.8M
#define KTOT  (IN_F + NC)         // 576: combined GEMM K

typedef __attribute__((ext_vector_type(8))) short bf16x8;
typedef __attribute__((ext_vector_type(4))) float f32x4;

static __device__ inline unsigned short f2bf(float f) {
    __hip_bfloat16 h = __float2bfloat16(f);   // RNE
    return *(unsigned short*)&h;
}

// ---------------------------------------------------------------------------
// K1: c_sum (atomicAdd into f32 csum, 32-way contention per address) + kl.
// 512 blocks x 1024 thr (VGPR<=64 -> 32 waves/CU potential), 8 rows/block,
// 16 KB contiguous span per (array,row). 24 nontemporal f32x4 loads/thread.
// NT loads are the R6 discovery: 74 -> 51 us; this round adds concurrency
// and kills the 8 MB part round-trip.
// ---------------------------------------------------------------------------
__global__ __launch_bounds__(1024)
void k1_partial(const float* __restrict__ cm,
                const float* __restrict__ clv,
                const float* __restrict__ eps,
                float* __restrict__ csum,
                float* __restrict__ klpart,
                int S) {
    int pb = blockIdx.x & 7;             // pair-slice: 4096 pairs (16 KB/row)
    int rc = blockIdx.x >> 3;            // 0..63: rows rc*8..+8
    int p4 = pb * 4096 + (threadIdx.x << 2);
    size_t base = (size_t)(rc * 8) * PAIRS + p4;
    float Sf = (float)S;

    f32x4 M[8], LV[8], ES[8];
#pragma unroll
    for (int ii = 0; ii < 8; ++ii)
        M[ii] = __builtin_nontemporal_load((const f32x4*)(cm + base + (size_t)ii * PAIRS));
#pragma unroll
    for (int ii = 0; ii < 8; ++ii)
        LV[ii] = __builtin_nontemporal_load((const f32x4*)(clv + base + (size_t)ii * PAIRS));
#pragma unroll
    for (int ii = 0; ii < 8; ++ii)
        ES[ii] = __builtin_nontemporal_load((const f32x4*)(eps + base + (size_t)ii * PAIRS));
    for (int si = 1; si < S; ++si)       // dead for S==1
#pragma unroll
        for (int ii = 0; ii < 8; ++ii) {
            f32x4 e = __builtin_nontemporal_load(
                (const f32x4*)(eps + (size_t)si * TOT + base + (size_t)ii * PAIRS));
            ES[ii] += e;
        }

    f32x4 s = {0.f, 0.f, 0.f, 0.f};
    float klp = 0.f;
#pragma unroll
    for (int ii = 0; ii < 8; ++ii) {
        float e1x = __expf(0.5f * LV[ii].x);
        float e1y = __expf(0.5f * LV[ii].y);
        float e1z = __expf(0.5f * LV[ii].z);
        float e1w = __expf(0.5f * LV[ii].w);
        s.x += Sf * M[ii].x + ES[ii].x * e1x;
        s.y += Sf * M[ii].y + ES[ii].y * e1y;
        s.z += Sf * M[ii].z + ES[ii].z * e1z;
        s.w += Sf * M[ii].w + ES[ii].w * e1w;
        klp += (e1x*e1x + M[ii].x*M[ii].x - 1.f - LV[ii].x);
        klp += (e1y*e1y + M[ii].y*M[ii].y - 1.f - LV[ii].y);
        klp += (e1z*e1z + M[ii].z*M[ii].z - 1.f - LV[ii].z);
        klp += (e1w*e1w + M[ii].w*M[ii].w - 1.f - LV[ii].w);
    }

    atomicAdd(&csum[p4 + 0], s.x);
    atomicAdd(&csum[p4 + 1], s.y);
    atomicAdd(&csum[p4 + 2], s.z);
    atomicAdd(&csum[p4 + 3], s.w);

    for (int off = 32; off; off >>= 1)
        klp += __shfl_down(klp, off, 64);
    __shared__ float wsum[16];
    if ((threadIdx.x & 63) == 0) wsum[threadIdx.x >> 6] = klp;
    __syncthreads();
    if (threadIdx.x == 0) {
        float t = 0.f;
#pragma unroll
        for (int i = 0; i < 16; ++i) t += wsum[i];
        klpart[blockIdx.x] = t;
    }
}

// ---------------------------------------------------------------------------
// K_mid: 401 blocks x 512 thr:
//   0..255   rbf                          | 256..319 W^T -> wct[*,0..511]
//   320..383 x f32->bf16 (xbf)            | 384 kl final (512 partials)
//   385..400 csum f32 -> wct[*,512..575]
// ---------------------------------------------------------------------------
__global__ __launch_bounds__(512)
void k_mid(const float* __restrict__ x,
           const float* __restrict__ centers,
           const float* __restrict__ log_sigma,
           const float* __restrict__ csum,
           const float* __restrict__ klpart,
           const float* __restrict__ bw,
           unsigned short* __restrict__ rbf,
           unsigned short* __restrict__ wct,
           unsigned short* __restrict__ xbf,
           float* __restrict__ kl_out,
           float inv_S) {
    __shared__ float shbuf[16 * 8 * 64];   // 32 KB, aliased per branch
    int bid = blockIdx.x, t = threadIdx.x;

    if (bid < 256) {
        // ---- rbf ----
        float (*red)[8][64] = (float (*)[8][64])shbuf;
        int n = t & 63;
        int wu = __builtin_amdgcn_readfirstlane(t >> 6);
        int b0 = bid * 16;

        float creg[64];
#pragma unroll
        for (int q = 0; q < 16; ++q) {
            float4 v = *(const float4*)(centers + (size_t)n * IN_F + wu * 64 + q * 4);
            creg[q * 4 + 0] = v.x; creg[q * 4 + 1] = v.y;
            creg[q * 4 + 2] = v.z; creg[q * 4 + 3] = v.w;
        }

        float dacc[16];
#pragma unroll
        for (int bi = 0; bi < 16; ++bi) {
            const float* xr = x + (size_t)(b0 + bi) * IN_F + wu * 64;
            float d0 = 0.f, d1 = 0.f, d2 = 0.f, d3 = 0.f;
#pragma unroll
            for (int j = 0; j < 64; j += 4) {
                float t0 = xr[j + 0] - creg[j + 0];
                float t1 = xr[j + 1] - creg[j + 1];
                float t2 = xr[j + 2] - creg[j + 2];
                float t3 = xr[j + 3] - creg[j + 3];
                d0 = fmaf(t0, t0, d0); d1 = fmaf(t1, t1, d1);
                d2 = fmaf(t2, t2, d2); d3 = fmaf(t3, t3, d3);
            }
            dacc[bi] = (d0 + d1) + (d2 + d3);
        }
#pragma unroll
        for (int bi = 0; bi < 16; ++bi)
            red[bi][wu][n] = dacc[bi];
        __syncthreads();
#pragma unroll
        for (int pass = 0; pass < 2; ++pass) {
            int idx = pass * 512 + t;
            int bi = idx >> 6, nn = idx & 63;
            float ssum = 0.f;
#pragma unroll
            for (int w = 0; w < 8; ++w) ssum += red[bi][w][nn];
            float sg  = __expf(log_sigma[nn]);
            float inv = 1.f / (2.f * sg * sg + 1e-8f);
            rbf[(size_t)(b0 + bi) * NC + nn] = f2bf(__expf(-ssum * inv));
        }
    } else if (bid < 320) {
        // ---- W transpose -> wct cols 0..511 ----
        float* tile = shbuf;               // 64 x 68
        int bb = bid - 256;
        int bi = bb >> 3, bj = bb & 7;
        int cq = t & 15, rq = t >> 4;      // rq 0..31
#pragma unroll
        for (int rr = 0; rr < 2; ++rr) {
            int row = rq * 2 + rr;
            float4 v = *(const float4*)(bw + (size_t)(bi * 64 + row) * OUT_F + bj * 64 + cq * 4);
            *(float4*)&tile[row * 68 + cq * 4] = v;
        }
        __syncthreads();
#pragma unroll
        for (int rr = 0; rr < 2; ++rr) {
            int orow = rq * 2 + rr;
            ushort4 w;
            w.x = f2bf(tile[(cq * 4 + 0) * 68 + orow]);
            w.y = f2bf(tile[(cq * 4 + 1) * 68 + orow]);
            w.z = f2bf(tile[(cq * 4 + 2) * 68 + orow]);
            w.w = f2bf(tile[(cq * 4 + 3) * 68 + orow]);
            *(ushort4*)(wct + (size_t)(bj * 64 + orow) * KTOT + bi * 64 + cq * 4) = w;
        }
    } else if (bid < 384) {
        // ---- x -> bf16 (xbf): 64 blocks x 32768 elems ----
        size_t base = (size_t)(bid - 320) * 32768;
#pragma unroll
        for (int q = 0; q < 16; ++q) {
            size_t off = base + q * 2048 + t * 4;
            float4 v = *(const float4*)(x + off);
            ushort4 w = {f2bf(v.x), f2bf(v.y), f2bf(v.z), f2bf(v.w)};
            *(ushort4*)(xbf + off) = w;
        }
    } else if (bid == 384) {
        // ---- kl final: 512 partials ----
        float v = klpart[t];
        for (int off = 32; off; off >>= 1)
            v += __shfl_down(v, off, 64);
        float* wsum = shbuf;
        if ((t & 63) == 0) wsum[t >> 6] = v;
        __syncthreads();
        if (t == 0) {
            float s = 0.f;
#pragma unroll
            for (int i = 0; i < 8; ++i) s += wsum[i];
            kl_out[0] = 0.5f * s;
        }
    } else {
        // ---- csum -> wct cols 512..575 (bf16, scaled): 16 blocks ----
        int p4 = (bid - 385) * 2048 + t * 4;
        float4 a = *(const float4*)(csum + p4);
        int o = p4 >> 6, n = p4 & 63;
        ushort4 w;
        w.x = f2bf(a.x * inv_S);
        w.y = f2bf(a.y * inv_S);
        w.z = f2bf(a.z * inv_S);
        w.w = f2bf(a.w * inv_S);
        *(ushort4*)(wct + (size_t)o * KTOT + IN_F + n) = w;
    }
}

// ---------------------------------------------------------------------------
// K3 v3: out = [xbf | rbf] @ Wc^T via mfma_f32_16x16x32_bf16.
// BM=BN=64, BK=64 -> grid 512 (2 blocks/CU for barrier overlap), 256 thr.
// 9 K-iterations (8 from xbf, 1 from rbf), 8 MFMA/wave/iter.
// LDS stride 72 bf16 (144 B rows, 16B-aligned frags; span structure same as
// the stride-40 layout that measured SQ_LDS_BANK_CONFLICT=0).
// ---------------------------------------------------------------------------
__global__ __launch_bounds__(256)
void k3_mfma(const unsigned short* __restrict__ xbf,
             const unsigned short* __restrict__ rbf,
             const unsigned short* __restrict__ wct,
             float* __restrict__ out) {
    __shared__ __align__(16) unsigned short As[64 * 72];   // 9 KB
    __shared__ __align__(16) unsigned short Bs[64 * 72];   // 9 KB
    int t = threadIdx.x;
    int bm = blockIdx.x >> 3, bn = blockIdx.x & 7;
    int b0 = bm * 64, o0 = bn * 64;
    int ar = t & 63, ah = t >> 6;        // staging: row, k-quarter(16)
    int lane = t & 63, wv = t >> 6;
    int fm = lane & 15, kg = lane >> 4;

    f32x4 acc[4] = {{0,0,0,0},{0,0,0,0},{0,0,0,0},{0,0,0,0}};
    const int abase = (wv * 16 + fm) * 72 + kg * 8;
    const int soff  = ar * 72 + ah * 16;

    for (int it = 0; it < 9; ++it) {
        bf16x8 av0, av1, bv0, bv1;
        if (it < 8) {
            int k0 = it * 64;
            av0 = *(const bf16x8*)(xbf + (size_t)(b0 + ar) * IN_F + k0 + ah * 16);
            av1 = *(const bf16x8*)(xbf + (size_t)(b0 + ar) * IN_F + k0 + ah * 16 + 8);
            bv0 = *(const bf16x8*)(wct + (size_t)(o0 + ar) * KTOT + k0 + ah * 16);
            bv1 = *(const bf16x8*)(wct + (size_t)(o0 + ar) * KTOT + k0 + ah * 16 + 8);
        } else {
            av0 = *(const bf16x8*)(rbf + (size_t)(b0 + ar) * NC + ah * 16);
            av1 = *(const bf16x8*)(rbf + (size_t)(b0 + ar) * NC + ah * 16 + 8);
            bv0 = *(const bf16x8*)(wct + (size_t)(o0 + ar) * KTOT + IN_F + ah * 16);
            bv1 = *(const bf16x8*)(wct + (size_t)(o0 + ar) * KTOT + IN_F + ah * 16 + 8);
        }
        __syncthreads();
        *(bf16x8*)&As[soff]     = av0;
        *(bf16x8*)&As[soff + 8] = av1;
        *(bf16x8*)&Bs[soff]     = bv0;
        *(bf16x8*)&Bs[soff + 8] = bv1;
        __syncthreads();
        bf16x8 af0 = *(bf16x8*)&As[abase];
        bf16x8 af1 = *(bf16x8*)&As[abase + 32];
#pragma unroll
        for (int nf = 0; nf < 4; ++nf) {
            bf16x8 b0f = *(bf16x8*)&Bs[(nf * 16 + fm) * 72 + kg * 8];
            acc[nf] = __builtin_amdgcn_mfma_f32_16x16x32_bf16(af0, b0f, acc[nf], 0, 0, 0);
            bf16x8 b1f = *(bf16x8*)&Bs[(nf * 16 + fm) * 72 + 32 + kg * 8];
            acc[nf] = __builtin_amdgcn_mfma_f32_16x16x32_bf16(af1, b1f, acc[nf], 0, 0, 0);
        }
    }

    // epilogue: C/D layout col=lane&15, row=(lane>>4)*4+reg
#pragma unroll
    for (int nf = 0; nf < 4; ++nf)
#pragma unroll
        for (int rr = 0; rr < 4; ++rr)
            out[(size_t)(b0 + wv * 16 + kg * 4 + rr) * OUT_F + o0 + nf * 16 + fm] = acc[nf][rr];
}

// ---------------------------------------------------------------------------
extern "C" void kernel_launch(void* const* d_in, const int* in_sizes, int n_in,
                              void* d_out, int out_size, void* d_ws, size_t ws_size,
                              hipStream_t stream) {
    const float* x         = (const float*)d_in[0];
    const float* centers   = (const float*)d_in[1];
    const float* log_sigma = (const float*)d_in[2];
    const float* cm        = (const float*)d_in[3];
    const float* clv       = (const float*)d_in[4];
    const float* bw        = (const float*)d_in[5];
    const float* eps       = (const float*)d_in[6];

    float* out = (float*)d_out;
    float* kl  = out + (size_t)B_SZ * OUT_F;

    // ws: [csum 128KB f32][klpart 2KB][WcT 576KB bf16][rbf 512KB bf16][xbf 4MB bf16]
    float* csum   = (float*)d_ws;
    float* klpart = csum + PAIRS;
    unsigned short* wct = (unsigned short*)(klpart + 512);
    unsigned short* rbf = wct + (size_t)OUT_F * KTOT;
    unsigned short* xbf = rbf + (size_t)B_SZ * NC;

    int S = in_sizes[6] / TOT;   // = 1

    hipMemsetAsync(csum, 0, PAIRS * sizeof(float), stream);  // atomic accumulator
    k1_partial<<<512, 1024, 0, stream>>>(cm, clv, eps, csum, klpart, S);
    k_mid<<<401, 512, 0, stream>>>(x, centers, log_sigma, csum, klpart, bw,
                                   rbf, wct, xbf, kl, 1.0f / (float)S);
    k3_mfma<<<(B_SZ / 64) * (OUT_F / 64), 256, 0, stream>>>(xbf, rbf, wct, out);
}

// Round 9
// 235.281 us; speedup vs baseline: 1.1451x; 1.1451x over previous
//
#include <hip/hip_runtime.h>
#include <hip/hip_bf16.h>

#define B_SZ  4096
#define IN_F  512
#define OUT_F 512
#define NC    64
#define PAIRS 32768               // OUT_F * NC
#define TOT   (IN_F * PAIRS)      // 16.8M
#define KTOT  (IN_F + NC)         // 576: combined GEMM K
#define RCH   32                  // k1 row-chunks (16 rows each)

typedef __attribute__((ext_vector_type(8))) short bf16x8;
typedef __attribute__((ext_vector_type(4))) float f32x4;

static __device__ inline unsigned short f2bf(float f) {
    __hip_bfloat16 h = __float2bfloat16(f);   // RNE
    return *(unsigned short*)&h;
}

// ---------------------------------------------------------------------------
// K1: partial c_sum + kl — EXACT R7 configuration (51 us, 2.05 TB/s HBM).
// 512 blocks x 512 thr, nontemporal f32x4 loads, plain partial stores
// (NO atomics: R8 proved cross-XCD atomicAdd costs +38 us via 32 MB
// write-through + line ping-pong). Do not touch.
// ---------------------------------------------------------------------------
__global__ __launch_bounds__(512)
void k1_partial(const float* __restrict__ cm,
                const float* __restrict__ clv,
                const float* __restrict__ eps,
                float* __restrict__ part,
                float* __restrict__ klpart,
                int S) {
    int pb = blockIdx.x & 15;            // pair-slice: 2048 pairs (8 KB/row)
    int rc = blockIdx.x >> 4;            // row-chunk: rows rc*16..+16
    int p4 = pb * 2048 + (threadIdx.x << 2);
    float Sf = (float)S;

    f32x4 s = {0.f, 0.f, 0.f, 0.f};
    float klp = 0.f;

    for (int g = 0; g < 2; ++g) {
        size_t base = (size_t)(rc * 16 + g * 8) * PAIRS + p4;
        f32x4 M[8], LV[8], ES[8];
#pragma unroll
        for (int ii = 0; ii < 8; ++ii)
            M[ii] = __builtin_nontemporal_load((const f32x4*)(cm + base + (size_t)ii * PAIRS));
#pragma unroll
        for (int ii = 0; ii < 8; ++ii)
            LV[ii] = __builtin_nontemporal_load((const f32x4*)(clv + base + (size_t)ii * PAIRS));
#pragma unroll
        for (int ii = 0; ii < 8; ++ii)
            ES[ii] = __builtin_nontemporal_load((const f32x4*)(eps + base + (size_t)ii * PAIRS));
        for (int si = 1; si < S; ++si)   // dead for S==1
#pragma unroll
            for (int ii = 0; ii < 8; ++ii) {
                f32x4 e = __builtin_nontemporal_load(
                    (const f32x4*)(eps + (size_t)si * TOT + base + (size_t)ii * PAIRS));
                ES[ii] += e;
            }

#pragma unroll
        for (int ii = 0; ii < 8; ++ii) {
            float e1x = __expf(0.5f * LV[ii].x);
            float e1y = __expf(0.5f * LV[ii].y);
            float e1z = __expf(0.5f * LV[ii].z);
            float e1w = __expf(0.5f * LV[ii].w);
            s.x += Sf * M[ii].x + ES[ii].x * e1x;
            s.y += Sf * M[ii].y + ES[ii].y * e1y;
            s.z += Sf * M[ii].z + ES[ii].z * e1z;
            s.w += Sf * M[ii].w + ES[ii].w * e1w;
            klp += (e1x*e1x + M[ii].x*M[ii].x - 1.f - LV[ii].x);
            klp += (e1y*e1y + M[ii].y*M[ii].y - 1.f - LV[ii].y);
            klp += (e1z*e1z + M[ii].z*M[ii].z - 1.f - LV[ii].z);
            klp += (e1w*e1w + M[ii].w*M[ii].w - 1.f - LV[ii].w);
        }
    }

    *(f32x4*)(part + (size_t)rc * PAIRS + p4) = s;

    for (int off = 32; off; off >>= 1)
        klp += __shfl_down(klp, off, 64);
    __shared__ float wsum[8];
    if ((threadIdx.x & 63) == 0) wsum[threadIdx.x >> 6] = klp;
    __syncthreads();
    if (threadIdx.x == 0) {
        float t = 0.f;
#pragma unroll
        for (int i = 0; i < 8; ++i) t += wsum[i];
        klpart[blockIdx.x] = t;
    }
}

// ---------------------------------------------------------------------------
// K_mid: 449 blocks x 512 thr:
//   0..255   rbf            | 256..319 csum reduce -> wct[*,512..575]
//   320..383 W^T -> wct     | 384 kl final
//   385..448 x f32 -> bf16  (xbf, for k3's A staging)
// ---------------------------------------------------------------------------
__global__ __launch_bounds__(512)
void k_mid(const float* __restrict__ x,
           const float* __restrict__ centers,
           const float* __restrict__ log_sigma,
           const float* __restrict__ part,
           const float* __restrict__ klpart,
           const float* __restrict__ bw,
           unsigned short* __restrict__ rbf,
           unsigned short* __restrict__ wct,
           unsigned short* __restrict__ xbf,
           float* __restrict__ kl_out,
           float inv_S) {
    __shared__ float shbuf[16 * 8 * 64];   // 32 KB, aliased per branch
    int bid = blockIdx.x, t = threadIdx.x;

    if (bid < 256) {
        // ---- rbf ----
        float (*red)[8][64] = (float (*)[8][64])shbuf;
        int n = t & 63;
        int wu = __builtin_amdgcn_readfirstlane(t >> 6);
        int b0 = bid * 16;

        float creg[64];
#pragma unroll
        for (int q = 0; q < 16; ++q) {
            float4 v = *(const float4*)(centers + (size_t)n * IN_F + wu * 64 + q * 4);
            creg[q * 4 + 0] = v.x; creg[q * 4 + 1] = v.y;
            creg[q * 4 + 2] = v.z; creg[q * 4 + 3] = v.w;
        }

        float dacc[16];
#pragma unroll
        for (int bi = 0; bi < 16; ++bi) {
            const float* xr = x + (size_t)(b0 + bi) * IN_F + wu * 64;
            float d0 = 0.f, d1 = 0.f, d2 = 0.f, d3 = 0.f;
#pragma unroll
            for (int j = 0; j < 64; j += 4) {
                float t0 = xr[j + 0] - creg[j + 0];
                float t1 = xr[j + 1] - creg[j + 1];
                float t2 = xr[j + 2] - creg[j + 2];
                float t3 = xr[j + 3] - creg[j + 3];
                d0 = fmaf(t0, t0, d0); d1 = fmaf(t1, t1, d1);
                d2 = fmaf(t2, t2, d2); d3 = fmaf(t3, t3, d3);
            }
            dacc[bi] = (d0 + d1) + (d2 + d3);
        }
#pragma unroll
        for (int bi = 0; bi < 16; ++bi)
            red[bi][wu][n] = dacc[bi];
        __syncthreads();
#pragma unroll
        for (int pass = 0; pass < 2; ++pass) {
            int idx = pass * 512 + t;
            int bi = idx >> 6, nn = idx & 63;
            float ssum = 0.f;
#pragma unroll
            for (int w = 0; w < 8; ++w) ssum += red[bi][w][nn];
            float sg  = __expf(log_sigma[nn]);
            float inv = 1.f / (2.f * sg * sg + 1e-8f);
            rbf[(size_t)(b0 + bi) * NC + nn] = f2bf(__expf(-ssum * inv));
        }
    } else if (bid < 320) {
        // ---- csum reduce: 64 blocks x 512 pairs ----
        int p = (bid - 256) * 512 + t;
        float a0 = 0.f, a1 = 0.f, a2 = 0.f, a3 = 0.f;
#pragma unroll
        for (int r = 0; r < RCH; r += 4) {
            a0 += part[(size_t)(r + 0) * PAIRS + p];
            a1 += part[(size_t)(r + 1) * PAIRS + p];
            a2 += part[(size_t)(r + 2) * PAIRS + p];
            a3 += part[(size_t)(r + 3) * PAIRS + p];
        }
        int o = p >> 6, n = p & 63;
        wct[(size_t)o * KTOT + IN_F + n] = f2bf(((a0 + a1) + (a2 + a3)) * inv_S);
    } else if (bid < 384) {
        // ---- W transpose -> wct cols 0..511 ----
        float* tile = shbuf;               // 64 x 68
        int bb = bid - 320;
        int bi = bb >> 3, bj = bb & 7;
        int cq = t & 15, rq = t >> 4;      // rq 0..31
#pragma unroll
        for (int rr = 0; rr < 2; ++rr) {
            int row = rq * 2 + rr;
            float4 v = *(const float4*)(bw + (size_t)(bi * 64 + row) * OUT_F + bj * 64 + cq * 4);
            *(float4*)&tile[row * 68 + cq * 4] = v;
        }
        __syncthreads();
#pragma unroll
        for (int rr = 0; rr < 2; ++rr) {
            int orow = rq * 2 + rr;
            ushort4 w;
            w.x = f2bf(tile[(cq * 4 + 0) * 68 + orow]);
            w.y = f2bf(tile[(cq * 4 + 1) * 68 + orow]);
            w.z = f2bf(tile[(cq * 4 + 2) * 68 + orow]);
            w.w = f2bf(tile[(cq * 4 + 3) * 68 + orow]);
            *(ushort4*)(wct + (size_t)(bj * 64 + orow) * KTOT + bi * 64 + cq * 4) = w;
        }
    } else if (bid == 384) {
        // ---- kl final: 512 partials ----
        float v = klpart[t];
        for (int off = 32; off; off >>= 1)
            v += __shfl_down(v, off, 64);
        float* wsum = shbuf;
        if ((t & 63) == 0) wsum[t >> 6] = v;
        __syncthreads();
        if (t == 0) {
            float s = 0.f;
#pragma unroll
            for (int i = 0; i < 8; ++i) s += wsum[i];
            kl_out[0] = 0.5f * s;
        }
    } else {
        // ---- x -> bf16 (xbf): 64 blocks x 32768 elems (x is L3/L2-warm) ----
        size_t base = (size_t)(bid - 385) * 32768;
#pragma unroll
        for (int q = 0; q < 16; ++q) {
            size_t off = base + q * 2048 + t * 4;
            float4 v = *(const float4*)(x + off);
            ushort4 w = {f2bf(v.x), f2bf(v.y), f2bf(v.z), f2bf(v.w)};
            *(ushort4*)(xbf + off) = w;
        }
    }
}

// ---------------------------------------------------------------------------
// K3 v3 (kept from R8 — non-k1 time improved 197 -> 180 us with it):
// out = [xbf | rbf] @ Wc^T via mfma_f32_16x16x32_bf16.
// BM=BN=64, BK=64 -> grid 512 (2 blocks/CU), 256 thr, 9 K-iters, 8 MFMA/iter.
// ---------------------------------------------------------------------------
__global__ __launch_bounds__(256)
void k3_mfma(const unsigned short* __restrict__ xbf,
             const unsigned short* __restrict__ rbf,
             const unsigned short* __restrict__ wct,
             float* __restrict__ out) {
    __shared__ __align__(16) unsigned short As[64 * 72];   // 9 KB
    __shared__ __align__(16) unsigned short Bs[64 * 72];   // 9 KB
    int t = threadIdx.x;
    int bm = blockIdx.x >> 3, bn = blockIdx.x & 7;
    int b0 = bm * 64, o0 = bn * 64;
    int ar = t & 63, ah = t >> 6;        // staging: row, k-quarter(16)
    int lane = t & 63, wv = t >> 6;
    int fm = lane & 15, kg = lane >> 4;

    f32x4 acc[4] = {{0,0,0,0},{0,0,0,0},{0,0,0,0},{0,0,0,0}};
    const int abase = (wv * 16 + fm) * 72 + kg * 8;
    const int soff  = ar * 72 + ah * 16;

    for (int it = 0; it < 9; ++it) {
        bf16x8 av0, av1, bv0, bv1;
        if (it < 8) {
            int k0 = it * 64;
            av0 = *(const bf16x8*)(xbf + (size_t)(b0 + ar) * IN_F + k0 + ah * 16);
            av1 = *(const bf16x8*)(xbf + (size_t)(b0 + ar) * IN_F + k0 + ah * 16 + 8);
            bv0 = *(const bf16x8*)(wct + (size_t)(o0 + ar) * KTOT + k0 + ah * 16);
            bv1 = *(const bf16x8*)(wct + (size_t)(o0 + ar) * KTOT + k0 + ah * 16 + 8);
        } else {
            av0 = *(const bf16x8*)(rbf + (size_t)(b0 + ar) * NC + ah * 16);
            av1 = *(const bf16x8*)(rbf + (size_t)(b0 + ar) * NC + ah * 16 + 8);
            bv0 = *(const bf16x8*)(wct + (size_t)(o0 + ar) * KTOT + IN_F + ah * 16);
            bv1 = *(const bf16x8*)(wct + (size_t)(o0 + ar) * KTOT + IN_F + ah * 16 + 8);
        }
        __syncthreads();
        *(bf16x8*)&As[soff]     = av0;
        *(bf16x8*)&As[soff + 8] = av1;
        *(bf16x8*)&Bs[soff]     = bv0;
        *(bf16x8*)&Bs[soff + 8] = bv1;
        __syncthreads();
        bf16x8 af0 = *(bf16x8*)&As[abase];
        bf16x8 af1 = *(bf16x8*)&As[abase + 32];
#pragma unroll
        for (int nf = 0; nf < 4; ++nf) {
            bf16x8 b0f = *(bf16x8*)&Bs[(nf * 16 + fm) * 72 + kg * 8];
            acc[nf] = __builtin_amdgcn_mfma_f32_16x16x32_bf16(af0, b0f, acc[nf], 0, 0, 0);
            bf16x8 b1f = *(bf16x8*)&Bs[(nf * 16 + fm) * 72 + 32 + kg * 8];
            acc[nf] = __builtin_amdgcn_mfma_f32_16x16x32_bf16(af1, b1f, acc[nf], 0, 0, 0);
        }
    }

    // epilogue: C/D layout col=lane&15, row=(lane>>4)*4+reg
#pragma unroll
    for (int nf = 0; nf < 4; ++nf)
#pragma unroll
        for (int rr = 0; rr < 4; ++rr)
            out[(size_t)(b0 + wv * 16 + kg * 4 + rr) * OUT_F + o0 + nf * 16 + fm] = acc[nf][rr];
}

// ---------------------------------------------------------------------------
extern "C" void kernel_launch(void* const* d_in, const int* in_sizes, int n_in,
                              void* d_out, int out_size, void* d_ws, size_t ws_size,
                              hipStream_t stream) {
    const float* x         = (const float*)d_in[0];
    const float* centers   = (const float*)d_in[1];
    const float* log_sigma = (const float*)d_in[2];
    const float* cm        = (const float*)d_in[3];
    const float* clv       = (const float*)d_in[4];
    const float* bw        = (const float*)d_in[5];
    const float* eps       = (const float*)d_in[6];

    float* out = (float*)d_out;
    float* kl  = out + (size_t)B_SZ * OUT_F;

    // ws: [part 4MB][klpart 2KB][WcT 576KB bf16][rbf 512KB bf16][xbf 4MB bf16]
    float* part   = (float*)d_ws;
    float* klpart = part + (size_t)RCH * PAIRS;
    unsigned short* wct = (unsigned short*)(klpart + 512);
    unsigned short* rbf = wct + (size_t)OUT_F * KTOT;
    unsigned short* xbf = rbf + (size_t)B_SZ * NC;

    int S = in_sizes[6] / TOT;   // = 1

    k1_partial<<<512, 512, 0, stream>>>(cm, clv, eps, part, klpart, S);
    k_mid<<<449, 512, 0, stream>>>(x, centers, log_sigma, part, klpart, bw,
                                   rbf, wct, xbf, kl, 1.0f / (float)S);
    k3_mfma<<<(B_SZ / 64) * (OUT_F / 64), 256, 0, stream>>>(xbf, rbf, wct, out);
}